// Round 4
// baseline (427.979 us; speedup 1.0000x reference)
//
#include <hip/hip_runtime.h>
#include <hip/hip_bf16.h>

// int4 weight-only quantized GEMV: out[n] = sum_k A[k] * W[n,k]
//   W[n,k] = (nib(B)[n,k] - 8) * scale[n, k/32] + zero[n, k/32]
// M=1, K=8192, N=16384, GROUP=32.
//
// Harness dtype canonicalization (confirmed R2/R3):
//   - reference f16 inputs arrive as FLOAT32 (A: [8192] f32, SZ: [N,256,2] f32)
//     (R2: bf16-packed decode NaN'd -> buffers are f32)
//   - reference f16 OUTPUT is read back as FLOAT32 ("bfloat16 -> bf16*, else
//     float*"). R3 wrote bf16 -> absmax 2324 == harness seeing out[2i+1] at
//     slot i. d_out is float*.
//   - B is int32 [N, K/2], one byte payload per int32 (low nibble = even k).
//
// One block per row n; thread t owns group t: 16 contiguous int32 of B (64 B),
// 32 floats of A (128 B, L1/L2-resident, shared by all blocks), 1 float2 of SZ.

__global__ __launch_bounds__(256) void gemv_w4(
    const float4* __restrict__ A4,   // 8192 f32 = 2048 float4
    const int4*   __restrict__ B,    // [N, 1024] int4-vectors (16B = 4 int32)
    const float2* __restrict__ SZ,   // [N, 256] (scale, zero) f32 pairs
    float* __restrict__ out,         // [N] f32
    int groups_per_row,              // 256
    int N)
{
    const int n = blockIdx.x;
    if (n >= N) return;
    const int t = threadIdx.x;

    // scale / zero for this thread's group (coalesced 8B/lane)
    const float2 sz = SZ[(size_t)n * groups_per_row + t];
    const float s = sz.x;
    const float z = sz.y;

    const int4*   Bp = B  + (size_t)n * (groups_per_row * 4) + t * 4;
    const float4* Ap = A4 + t * 8;   // k in [32t, 32t+32) -> 8 float4

    float dot = 0.0f;  // sum A[k] * nib[k]
    float sA  = 0.0f;  // sum A[k]
#pragma unroll
    for (int j = 0; j < 4; ++j) {
        const int4   b  = Bp[j];           // int32 idx 16t+4j.. -> k = 32t+8j..+7
        const float4 a0 = Ap[2 * j];       // A[32t+8j .. +3]
        const float4 a1 = Ap[2 * j + 1];   // A[32t+8j+4 .. +7]
        const int   bb[4] = { b.x, b.y, b.z, b.w };
        const float aa[8] = { a0.x, a0.y, a0.z, a0.w, a1.x, a1.y, a1.z, a1.w };
#pragma unroll
        for (int m = 0; m < 4; ++m) {
            const float alo = aa[2 * m];       // k even -> low nibble
            const float ahi = aa[2 * m + 1];   // k odd  -> high nibble
            dot = fmaf(alo, (float)(bb[m] & 0xF), dot);
            dot = fmaf(ahi, (float)((bb[m] >> 4) & 0xF), dot);
            sA += alo + ahi;
        }
    }
    // W = nib*s + (z - 8s)  =>  contribution = s*dot + (z - 8s)*sA
    float part = fmaf(s, dot, (z - 8.0f * s) * sA);

    // 256 -> 1 reduction: wave shuffle, then LDS across 4 waves
#pragma unroll
    for (int off = 32; off > 0; off >>= 1)
        part += __shfl_down(part, off, 64);

    __shared__ float red[4];
    if ((t & 63) == 0) red[t >> 6] = part;
    __syncthreads();
    if (t == 0) {
        out[n] = red[0] + red[1] + red[2] + red[3];
    }
}

extern "C" void kernel_launch(void* const* d_in, const int* in_sizes, int n_in,
                              void* d_out, int out_size, void* d_ws, size_t ws_size,
                              hipStream_t stream) {
    const float4* A4 = (const float4*)d_in[0];   // f32[8192]
    const int4*   B  = (const int4*)d_in[1];     // int32[N, 4096]
    const float2* SZ = (const float2*)d_in[2];   // f32[N, 256, 2]
    float* out = (float*)d_out;                  // f32[N]

    const int N = out_size;                      // 16384
    const int Kh = in_sizes[1] / N;              // 4096
    const int groups = (2 * Kh) / 32;            // 256

    gemv_w4<<<N, 256, 0, stream>>>(A4, B, SZ, out, groups, N);
}

// Round 5
// 373.490 us; speedup vs baseline: 1.1459x; 1.1459x over previous
//
#include <hip/hip_runtime.h>
#include <hip/hip_bf16.h>

// int4 weight-only quantized GEMV: out[n] = sum_k A[k] * W[n,k]
//   W[n,k] = (nib(B)[n,k] - 8) * scale[n, k/32] + zero[n, k/32]
// M=1, K=8192, N=16384, GROUP=32.
//
// Dtypes (confirmed R2-R4): A [8192] f32, B [N, K/2] int32 (1 byte payload,
// low nibble = even k), SZ [N, 256, 2] f32, out [N] f32.
//
// R4 post-mortem: one-block-per-row was latency/transaction-bound (940 GB/s,
// VALUBusy 10%): 64B-lane-stride B loads (32 lines/instr) + full A reload per
// block (8 loads/thread/row). This version: ROWS=8 rows/block, A slice held in
// registers (loaded once, amortized 8x), B loads lane-contiguous (1KiB/instr).
//
// Thread t owns k-slices [8*(t+256j), 8*(t+256j)+8) for j=0..3, which exactly
// matches B int4 index t+256j (int4 = 4 int32 = 8 k). Group of that slice is
// (t>>2) + 64j (8 k-values always within one 32-wide group since 8t%32==0 per
// 4-thread cluster... (t+256j)*8/32 = (t+256j)/4 -> same for lanes 4m..4m+3).

#define ROWS 8

__global__ __launch_bounds__(256) void gemv_w4r(
    const float4* __restrict__ A4,   // 8192 f32 = 2048 float4
    const int4*   __restrict__ B,    // [N, 1024] int4 (16B = 4 int32 = 8 k)
    const float2* __restrict__ SZ,   // [N, 256] (scale, zero) f32 pairs
    float* __restrict__ out,         // [N] f32
    int N)
{
    const int t  = threadIdx.x;
    const int n0 = blockIdx.x * ROWS;

    // ---- A slice -> registers, once per block (amortized over ROWS rows) ----
    float a[4][8];
    float sAj[4];
#pragma unroll
    for (int j = 0; j < 4; ++j) {
        const float4 x = A4[2 * t + 512 * j];
        const float4 y = A4[2 * t + 512 * j + 1];
        a[j][0] = x.x; a[j][1] = x.y; a[j][2] = x.z; a[j][3] = x.w;
        a[j][4] = y.x; a[j][5] = y.y; a[j][6] = y.z; a[j][7] = y.w;
        sAj[j] = ((x.x + x.y) + (x.z + x.w)) + ((y.x + y.y) + (y.z + y.w));
    }

    __shared__ float red[ROWS][4];
    const int lane = t & 63;
    const int w    = t >> 6;

    float acc[ROWS];
#pragma unroll
    for (int r = 0; r < ROWS; ++r) acc[r] = 0.0f;

    for (int r = 0; r < ROWS; ++r) {
        const int n = n0 + r;
        const int4*   Bp = B  + (size_t)n * 1024;
        const float2* Sp = SZ + (size_t)n * 256 + (t >> 2);

        float part = 0.0f;
#pragma unroll
        for (int j = 0; j < 4; ++j) {
            const int4   b  = Bp[t + 256 * j];        // coalesced: 16B/lane
            const float2 sz = Sp[64 * j];             // 4-lane broadcast
            const int bb[4] = { b.x, b.y, b.z, b.w };
            float dot = 0.0f;
#pragma unroll
            for (int m = 0; m < 4; ++m) {
                dot = fmaf(a[j][2 * m],     (float)(bb[m] & 0xF),        dot);
                dot = fmaf(a[j][2 * m + 1], (float)((bb[m] >> 4) & 0xF), dot);
            }
            const float zz = fmaf(-8.0f, sz.x, sz.y);   // z - 8s
            part = fmaf(sz.x, dot, part);
            part = fmaf(zz, sAj[j], part);
        }
        acc[r] = part;
    }

    // ---- reduce: wave shuffle per row, stage in LDS, one barrier ----
#pragma unroll
    for (int r = 0; r < ROWS; ++r) {
        float v = acc[r];
#pragma unroll
        for (int off = 32; off > 0; off >>= 1)
            v += __shfl_down(v, off, 64);
        if (lane == 0) red[r][w] = v;
    }
    __syncthreads();
    if (t < ROWS) {
        const int n = n0 + t;
        if (n < N)
            out[n] = (red[t][0] + red[t][1]) + (red[t][2] + red[t][3]);
    }
}

extern "C" void kernel_launch(void* const* d_in, const int* in_sizes, int n_in,
                              void* d_out, int out_size, void* d_ws, size_t ws_size,
                              hipStream_t stream) {
    const float4* A4 = (const float4*)d_in[0];   // f32[8192]
    const int4*   B  = (const int4*)d_in[1];     // int32[N, 4096]
    const float2* SZ = (const float2*)d_in[2];   // f32[N, 256, 2]
    float* out = (float*)d_out;                  // f32[N]

    const int N = out_size;                      // 16384
    gemv_w4r<<<N / ROWS, 256, 0, stream>>>(A4, B, SZ, out, N);
}